// Round 1
// baseline (1022.058 us; speedup 1.0000x reference)
//
#include <hip/hip_runtime.h>
#include <hip/hip_cooperative_groups.h>
#include <hip/hip_bf16.h>

namespace cg = cooperative_groups;

#define H  1024
#define L  4096
#define V  50257

#define NB 512      // cooperative grid: 2 blocks/CU x 256 CU
#define NT 256

// workspace layout (floats)
#define OFF_QW     0                    // 1024   query @ Wq
#define OFF_SCORES 1024                 // 4096   raw scores (pre-softmax)
#define OFF_X      5120                 // 2048   x = concat(context, emb_relu)
#define OFF_GI0    7168                 // 3072
#define OFF_GH0    10240                // 3072
#define OFF_GI1    13312                // 3072
#define OFF_GH1    16384                // 3072
#define OFF_LOGITS 19456                // V
#define OFF_PMAX   (OFF_LOGITS + V)     // 69713  per-block max partials (NB)
#define OFF_PSUM   (OFF_PMAX + NB)      // 70225  per-block sum partials (NB)
#define ZERO_FLOATS (OFF_LOGITS + V)    // fallback path memset extent
#define OFF_WKT_BYTES 283008            // 16B-aligned, > (OFF_PSUM+NB)*4; bf16 WkT[1024][1024] = 2 MB

typedef __bf16 bf8   __attribute__((ext_vector_type(8)));
typedef float  f32x16 __attribute__((ext_vector_type(16)));

__device__ inline unsigned int pack_bf16x2(float lo, float hi) {
    unsigned int ulo = __builtin_bit_cast(unsigned int, lo);
    unsigned int uhi = __builtin_bit_cast(unsigned int, hi);
    return ((uhi + 0x8000u) & 0xFFFF0000u) | ((ulo + 0x8000u) >> 16);
}
__device__ inline unsigned short cvt_bf16(float f) {
    unsigned int u = __builtin_bit_cast(unsigned int, f);
    return (unsigned short)((u + 0x8000u) >> 16);
}

struct Prm {
    const int*   tok;
    const float* hid;
    const float* enc;
    const float* emb;
    const float* Wq;
    const float* Wk;
    const float* wv;
    const float* Wih0;
    const float* Whh0;
    const float* bih0;
    const float* bhh0;
    const float* Wih1;
    const float* Whh1;
    const float* bih1;
    const float* bhh1;
    const float* Wd;
    const float* bd;
    float* out;
    float* ws;
    unsigned short* wkT;
};

// =================== single fused cooperative kernel ===================
// P0: zero accumulators | embed+relu | qW (atomic-free) | WkT transpose | gh0 | gh1
// P1: scores bf16-MFMA GEMM + tanh/wv epilogue (atomic into scores)
// P2: softmax + context (atomic into x[0:H))
// P3: gi0 = Wih0 @ x
// P4: combine0 -> h0n ; gi1 = Wih1 @ h0n
// P5: combine1 -> h1n ; logits = h1n @ Wd + bd (atomic, 2 ILP streams/thread)
// P6: 3-subphase parallel log_softmax
__global__ __launch_bounds__(NT, 2) void k_all(Prm p) {
    cg::grid_group gg = cg::this_grid();
    const int bid = blockIdx.x, t = threadIdx.x;
    float* __restrict__ ws = p.ws;

    __shared__ float tile[32][33];
    __shared__ unsigned short As[64][40];    // [m][k] bf16, +8 pad
    __shared__ unsigned short Bs[128][40];   // [n][k] bf16
    __shared__ float xs[H];                  // h0n in P4, h1n in P5
    __shared__ float red[16];

    // ---------------- P0 ----------------
    {   // zero atomic targets (used only in later phases, after grid.sync)
        int g = bid * NT + t;                       // 0 .. 131071
        if (g < 4096) ws[OFF_SCORES + g] = 0.f;
        if (g < 1024) ws[OFF_X + g] = 0.f;
        if (g < V)    ws[OFF_LOGITS + g] = 0.f;
    }
    // virtual blocks: [0,4) embed | [4,8) qW | [8,1032) WkT | [1032,1800) gh0 | [1800,2568) gh1
    for (int vb = bid; vb < 2568; vb += NB) {
        if (vb < 4) {
            int j = vb * 256 + t;
            float v = p.emb[(size_t)p.tok[0] * H + j];
            ws[OFF_X + H + j] = fmaxf(v, 0.f);
        } else if (vb < 8) {
            // qW[j] = sum_i q[i] * Wq[i][j]  (direct store, no atomics)
            int j = (vb - 4) * 256 + t;
            const float* q = p.hid + H;
            float acc = 0.f;
#pragma unroll 8
            for (int i = 0; i < H; ++i) acc += q[i] * p.Wq[(size_t)i * H + j];
            ws[OFF_QW + j] = acc;
        } else if (vb < 1032) {
            int tt = vb - 8, tk = tt & 31, tn = tt >> 5;   // 32x32 tile grid
            int c = t & 31, r0 = t >> 5;
#pragma unroll
            for (int rr = 0; rr < 4; ++rr) {
                int r = r0 + rr * 8;
                tile[r][c] = p.Wk[(size_t)(tk * 32 + r) * H + tn * 32 + c];
            }
            __syncthreads();
#pragma unroll
            for (int rr = 0; rr < 4; ++rr) {
                int rn = r0 + rr * 8;
                p.wkT[(size_t)(tn * 32 + rn) * H + tk * 32 + c] = cvt_bf16(tile[c][rn]);
            }
            __syncthreads();                       // protect tile across vb iterations
        } else {
            // gh0 / gh1 depend only on inputs -> hoisted into P0
            bool l1 = (vb >= 1800);
            int row  = (vb - (l1 ? 1800 : 1032)) * 4 + (t >> 6);
            int lane = t & 63;
            const float*  W  = l1 ? p.Whh1 : p.Whh0;
            const float*  b  = l1 ? p.bhh1 : p.bhh0;
            const float4* hv = (const float4*)(l1 ? p.hid + H : p.hid);
            const float4* Wr = (const float4*)(W + (size_t)row * H);
            float acc = 0.f;
#pragma unroll
            for (int c = lane; c < H / 4; c += 64) {
                float4 w = Wr[c], x = hv[c];
                acc += w.x * x.x + w.y * x.y + w.z * x.z + w.w * x.w;
            }
#pragma unroll
            for (int off = 32; off; off >>= 1) acc += __shfl_down(acc, off);
            if (lane == 0) ws[(l1 ? OFF_GH1 : OFF_GH0) + row] = acc + b[row];
        }
    }
    gg.sync();

    // ---------------- P1: scores GEMM (tile 64x128, K-step 32) ----------------
    for (int vb = bid; vb < 512; vb += NB) {
        const int lane = t & 63, w = t >> 6;
        const int m0 = (vb & 63) * 64, n0 = (vb >> 6) * 128;
        f32x16 acc0 = {}, acc1 = {};
        const int ar = t >> 2, akq = (t & 3) * 8;
        const int bn = t >> 1, bkh = (t & 1) * 16;
        const int r0 = (w & 1) * 32, c0 = (w >> 1) * 64;
        const int mrow = r0 + (lane & 31);
        const int nrow0 = c0 + (lane & 31), nrow1 = nrow0 + 32;

        for (int k0 = 0; k0 < H; k0 += 32) {
            float4 fa = *(const float4*)(p.enc + (size_t)(m0 + ar) * H + k0 + akq);
            float4 fb = *(const float4*)(p.enc + (size_t)(m0 + ar) * H + k0 + akq + 4);
            uint4 wb0 = *(const uint4*)(p.wkT + (size_t)(n0 + bn) * H + k0 + bkh);
            uint4 wb1 = *(const uint4*)(p.wkT + (size_t)(n0 + bn) * H + k0 + bkh + 8);
            __syncthreads();                       // prev-iter LDS reads done
            uint4 pa;
            pa.x = pack_bf16x2(fa.x, fa.y); pa.y = pack_bf16x2(fa.z, fa.w);
            pa.z = pack_bf16x2(fb.x, fb.y); pa.w = pack_bf16x2(fb.z, fb.w);
            *(uint4*)&As[ar][akq] = pa;
            *(uint4*)&Bs[bn][bkh] = wb0;
            *(uint4*)&Bs[bn][bkh + 8] = wb1;
            __syncthreads();
#pragma unroll
            for (int kk = 0; kk < 2; ++kk) {
                int kb = kk * 16 + (lane >> 5) * 8;
                bf8 a  = *(const bf8*)&As[mrow][kb];
                bf8 b0 = *(const bf8*)&Bs[nrow0][kb];
                bf8 b1 = *(const bf8*)&Bs[nrow1][kb];
                acc0 = __builtin_amdgcn_mfma_f32_32x32x16_bf16(a, b0, acc0, 0, 0, 0);
                acc1 = __builtin_amdgcn_mfma_f32_32x32x16_bf16(a, b1, acc1, 0, 0, 0);
            }
        }
        const int n_a = n0 + nrow0, n_b = n0 + nrow1;
        float qwa = ws[OFF_QW + n_a], qwb = ws[OFF_QW + n_b];
        float wva = p.wv[n_a], wvb = p.wv[n_b];
        const int rbase = m0 + r0 + 4 * (lane >> 5);
#pragma unroll
        for (int reg = 0; reg < 16; ++reg) {
            float s = tanhf(acc0[reg] + qwa) * wva + tanhf(acc1[reg] + qwb) * wvb;
#pragma unroll
            for (int msk = 1; msk < 32; msk <<= 1) s += __shfl_xor(s, msk);
            if ((lane & 31) == 0)
                atomicAdd(&ws[OFF_SCORES + rbase + (reg & 3) + 8 * (reg >> 2)], s);
        }
    }
    gg.sync();

    // ---------------- P2: softmax + context ----------------
    for (int vb = bid; vb < 512; vb += NB) {     // 4 h-blocks x 128 l-splits of 32
        const float* sc = ws + OFF_SCORES;
        float m = -1e30f;
#pragma unroll
        for (int i = 0; i < 16; ++i) m = fmaxf(m, sc[t + i * 256]);
#pragma unroll
        for (int msk = 1; msk < 64; msk <<= 1) m = fmaxf(m, __shfl_xor(m, msk));
        if ((t & 63) == 0) red[t >> 6] = m;
        __syncthreads();
        m = fmaxf(fmaxf(red[0], red[1]), fmaxf(red[2], red[3]));
        __syncthreads();
        float s = 0.f;
#pragma unroll
        for (int i = 0; i < 16; ++i) s += expf(sc[t + i * 256] - m);
#pragma unroll
        for (int msk = 1; msk < 64; msk <<= 1) s += __shfl_xor(s, msk);
        if ((t & 63) == 0) red[t >> 6] = s;
        __syncthreads();
        float inv = 1.f / (red[0] + red[1] + red[2] + red[3]);

        const int h = (vb & 3) * 256 + t;
        const int l0 = (vb >> 2) * 32;
        float acc = 0.f;
#pragma unroll 4
        for (int l = l0; l < l0 + 32; ++l)
            acc += expf(sc[l] - m) * p.enc[(size_t)l * H + h];
        atomicAdd(&ws[OFF_X + h], acc * inv);
        __syncthreads();
    }
    gg.sync();

    // ---------------- P3: gi0 = Wih0 @ x ----------------
    for (int vb = bid; vb < 768; vb += NB) {
        int row = vb * 4 + (t >> 6), lane = t & 63;
        const float4* Wr = (const float4*)(p.Wih0 + (size_t)row * (2 * H));
        const float4* x4 = (const float4*)(ws + OFF_X);
        float acc = 0.f;
#pragma unroll
        for (int c = lane; c < 2 * H / 4; c += 64) {
            float4 w = Wr[c], x = x4[c];
            acc += w.x * x.x + w.y * x.y + w.z * x.z + w.w * x.w;
        }
#pragma unroll
        for (int off = 32; off; off >>= 1) acc += __shfl_down(acc, off);
        if (lane == 0) ws[OFF_GI0 + row] = acc + p.bih0[row];
    }
    gg.sync();

    // ---------------- P4: combine0 -> h0n ; gi1 = Wih1 @ h0n ----------------
    {
#pragma unroll
        for (int jj = 0; jj < 4; ++jj) {
            int j = t + jj * 256;
            float r = 1.f / (1.f + expf(-(ws[OFF_GI0 + j] + ws[OFF_GH0 + j])));
            float z = 1.f / (1.f + expf(-(ws[OFF_GI0 + H + j] + ws[OFF_GH0 + H + j])));
            float n = tanhf(ws[OFF_GI0 + 2 * H + j] + r * ws[OFF_GH0 + 2 * H + j]);
            float h0 = (1.f - z) * n + z * p.hid[j];
            xs[j] = h0;
            if (bid == 0) p.out[V + j] = h0;
        }
        __syncthreads();
        for (int vb = bid; vb < 768; vb += NB) {
            int row = vb * 4 + (t >> 6), lane = t & 63;
            const float4* Wr = (const float4*)(p.Wih1 + (size_t)row * H);
            float acc = 0.f;
#pragma unroll
            for (int c = lane; c < H / 4; c += 64) {
                float4 w = Wr[c];
                float4 x = *(const float4*)&xs[c * 4];
                acc += w.x * x.x + w.y * x.y + w.z * x.z + w.w * x.w;
            }
#pragma unroll
            for (int off = 32; off; off >>= 1) acc += __shfl_down(acc, off);
            if (lane == 0) ws[OFF_GI1 + row] = acc + p.bih1[row];
        }
    }
    gg.sync();

    // ---------------- P5: combine1 -> h1n ; logits ----------------
    {
#pragma unroll
        for (int jj = 0; jj < 4; ++jj) {
            int j = t + jj * 256;
            float r = 1.f / (1.f + expf(-(ws[OFF_GI1 + j] + ws[OFF_GH1 + j])));
            float z = 1.f / (1.f + expf(-(ws[OFF_GI1 + H + j] + ws[OFF_GH1 + H + j])));
            float n = tanhf(ws[OFF_GI1 + 2 * H + j] + r * ws[OFF_GH1 + 2 * H + j]);
            float h1 = (1.f - z) * n + z * p.hid[H + j];
            xs[j] = h1;
            if (bid == 0) p.out[V + H + j] = h1;
        }
        __syncthreads();
        const int NV5 = (V + 511) / 512;          // 99 v-blocks of 512
        for (int vb = bid; vb < NV5 * 8; vb += NB) {
            int v0 = (vb >> 3) * 512, k0 = (vb & 7) * 128;
            int va = v0 + t, vb2 = v0 + 256 + t;
            int vac = va  < V ? va  : V - 1;      // clamp: harmless dup loads in tail
            int vbc = vb2 < V ? vb2 : V - 1;
            float acca = 0.f, accb = 0.f;
            const float* Wp = p.Wd + (size_t)k0 * V;
#pragma unroll 8
            for (int k = 0; k < 128; ++k) {       // 2 streams -> 16 loads in flight
                float xk = xs[k0 + k];
                const float* row = Wp + (size_t)k * V;
                acca += xk * row[vac];
                accb += xk * row[vbc];
            }
            if (va  < V) atomicAdd(&ws[OFF_LOGITS + va],  acca + (k0 == 0 ? p.bd[va]  : 0.f));
            if (vb2 < V) atomicAdd(&ws[OFF_LOGITS + vb2], accb + (k0 == 0 ? p.bd[vb2] : 0.f));
        }
    }
    gg.sync();

    // ---------------- P6: log_softmax (parallel, 3 subphases) ----------------
    float gmax;
    {   // P6a: per-block max partial (one element per thread: NB*NT >= V)
        int g = bid * NT + t;
        float m = (g < V) ? ws[OFF_LOGITS + g] : -1e30f;
#pragma unroll
        for (int msk = 1; msk < 64; msk <<= 1) m = fmaxf(m, __shfl_xor(m, msk));
        if ((t & 63) == 0) red[t >> 6] = m;
        __syncthreads();
        if (t == 0) ws[OFF_PMAX + bid] = fmaxf(fmaxf(red[0], red[1]), fmaxf(red[2], red[3]));
    }
    gg.sync();
    {   // P6b: global max, then per-block exp-sum partial
        float m = -1e30f;
        for (int i = t; i < NB; i += NT) m = fmaxf(m, ws[OFF_PMAX + i]);
#pragma unroll
        for (int msk = 1; msk < 64; msk <<= 1) m = fmaxf(m, __shfl_xor(m, msk));
        if ((t & 63) == 0) red[t >> 6] = m;
        __syncthreads();
        gmax = fmaxf(fmaxf(red[0], red[1]), fmaxf(red[2], red[3]));
        __syncthreads();
        int g = bid * NT + t;
        float s = (g < V) ? expf(ws[OFF_LOGITS + g] - gmax) : 0.f;
#pragma unroll
        for (int msk = 1; msk < 64; msk <<= 1) s += __shfl_xor(s, msk);
        if ((t & 63) == 0) red[t >> 6] = s;
        __syncthreads();
        if (t == 0) ws[OFF_PSUM + bid] = red[0] + red[1] + red[2] + red[3];
    }
    gg.sync();
    {   // P6c: lse + write output
        float s = 0.f;
        for (int i = t; i < NB; i += NT) s += ws[OFF_PSUM + i];
#pragma unroll
        for (int msk = 1; msk < 64; msk <<= 1) s += __shfl_xor(s, msk);
        if ((t & 63) == 0) red[t >> 6] = s;
        __syncthreads();
        float lse = gmax + logf(red[0] + red[1] + red[2] + red[3]);
        int g = bid * NT + t;
        if (g < V) p.out[g] = ws[OFF_LOGITS + g] - lse;
    }
}

// =====================================================================
// ============== fallback path: original 8-dispatch chain =============
// =====================================================================
__global__ __launch_bounds__(256) void k_prep(const int* __restrict__ tok,
                                              const float* __restrict__ emb,
                                              const float* __restrict__ hid,
                                              const float* __restrict__ Wq,
                                              const float* __restrict__ Wk,
                                              float* __restrict__ ws,
                                              unsigned short* __restrict__ wkT) {
    __shared__ float tile[32][33];
    const int b = blockIdx.x, t = threadIdx.x;
    if (b < 4) {
        int j = b * 256 + t;
        float v = emb[(size_t)tok[0] * H + j];
        ws[OFF_X + H + j] = fmaxf(v, 0.f);
    } else if (b < 68) {
        int bb = b - 4;
        int j = (bb & 3) * 256 + t;
        int i0 = (bb >> 2) * 64;
        const float* q = hid + H;
        float acc = 0.f;
#pragma unroll 8
        for (int i = i0; i < i0 + 64; ++i) acc += q[i] * Wq[i * H + j];
        atomicAdd(&ws[OFF_QW + j], acc);
    } else {
        int tt = b - 68;
        int tk = tt & 31, tn = tt >> 5;
        int c = t & 31, r0 = t >> 5;
#pragma unroll
        for (int rr = 0; rr < 4; ++rr) {
            int r = r0 + rr * 8;
            tile[r][c] = Wk[(size_t)(tk * 32 + r) * H + tn * 32 + c];
        }
        __syncthreads();
#pragma unroll
        for (int rr = 0; rr < 4; ++rr) {
            int rn = r0 + rr * 8;
            wkT[(size_t)(tn * 32 + rn) * H + tk * 32 + c] = cvt_bf16(tile[c][rn]);
        }
    }
}

__global__ __launch_bounds__(256) void k_gemm_scores(const float* __restrict__ enc,
                                                     const unsigned short* __restrict__ wkT,
                                                     const float* __restrict__ wv,
                                                     float* __restrict__ ws) {
    __shared__ unsigned short As[64][40];
    __shared__ unsigned short Bs[128][40];
    const int t = threadIdx.x, lane = t & 63, w = t >> 6;
    const int m0 = blockIdx.x * 64, n0 = blockIdx.y * 128;
    f32x16 acc0 = {}, acc1 = {};
    const int ar = t >> 2, akq = (t & 3) * 8;
    const int bn = t >> 1, bkh = (t & 1) * 16;
    const int r0 = (w & 1) * 32, c0 = (w >> 1) * 64;
    const int mrow = r0 + (lane & 31);
    const int nrow0 = c0 + (lane & 31), nrow1 = nrow0 + 32;
    for (int k0 = 0; k0 < H; k0 += 32) {
        float4 fa = *(const float4*)(enc + (size_t)(m0 + ar) * H + k0 + akq);
        float4 fb = *(const float4*)(enc + (size_t)(m0 + ar) * H + k0 + akq + 4);
        uint4 wb0 = *(const uint4*)(wkT + (size_t)(n0 + bn) * H + k0 + bkh);
        uint4 wb1 = *(const uint4*)(wkT + (size_t)(n0 + bn) * H + k0 + bkh + 8);
        __syncthreads();
        uint4 pa;
        pa.x = pack_bf16x2(fa.x, fa.y); pa.y = pack_bf16x2(fa.z, fa.w);
        pa.z = pack_bf16x2(fb.x, fb.y); pa.w = pack_bf16x2(fb.z, fb.w);
        *(uint4*)&As[ar][akq] = pa;
        *(uint4*)&Bs[bn][bkh] = wb0;
        *(uint4*)&Bs[bn][bkh + 8] = wb1;
        __syncthreads();
#pragma unroll
        for (int kk = 0; kk < 2; ++kk) {
            int kb = kk * 16 + (lane >> 5) * 8;
            bf8 a  = *(const bf8*)&As[mrow][kb];
            bf8 b0 = *(const bf8*)&Bs[nrow0][kb];
            bf8 b1 = *(const bf8*)&Bs[nrow1][kb];
            acc0 = __builtin_amdgcn_mfma_f32_32x32x16_bf16(a, b0, acc0, 0, 0, 0);
            acc1 = __builtin_amdgcn_mfma_f32_32x32x16_bf16(a, b1, acc1, 0, 0, 0);
        }
    }
    const int n_a = n0 + nrow0, n_b = n0 + nrow1;
    float qwa = ws[OFF_QW + n_a], qwb = ws[OFF_QW + n_b];
    float wva = wv[n_a], wvb = wv[n_b];
    const int rbase = m0 + r0 + 4 * (lane >> 5);
#pragma unroll
    for (int reg = 0; reg < 16; ++reg) {
        float s = tanhf(acc0[reg] + qwa) * wva + tanhf(acc1[reg] + qwb) * wvb;
#pragma unroll
        for (int msk = 1; msk < 32; msk <<= 1) s += __shfl_xor(s, msk);
        if ((lane & 31) == 0) {
            int l = rbase + (reg & 3) + 8 * (reg >> 2);
            atomicAdd(&ws[OFF_SCORES + l], s);
        }
    }
}

__global__ __launch_bounds__(256) void k_context(const float* __restrict__ enc,
                                                 float* __restrict__ ws) {
    __shared__ float red[4];
    const int t = threadIdx.x;
    const float* sc = ws + OFF_SCORES;
    float m = -1e30f;
#pragma unroll
    for (int i = 0; i < 16; ++i) m = fmaxf(m, sc[t + i * 256]);
#pragma unroll
    for (int msk = 1; msk < 64; msk <<= 1) m = fmaxf(m, __shfl_xor(m, msk));
    if ((t & 63) == 0) red[t >> 6] = m;
    __syncthreads();
    m = fmaxf(fmaxf(red[0], red[1]), fmaxf(red[2], red[3]));
    __syncthreads();
    float s = 0.f;
#pragma unroll
    for (int i = 0; i < 16; ++i) s += expf(sc[t + i * 256] - m);
#pragma unroll
    for (int msk = 1; msk < 64; msk <<= 1) s += __shfl_xor(s, msk);
    if ((t & 63) == 0) red[t >> 6] = s;
    __syncthreads();
    float inv = 1.f / (red[0] + red[1] + red[2] + red[3]);
    const int h = blockIdx.x * 256 + t;
    const int l0 = blockIdx.y * 128;
    float acc = 0.f;
#pragma unroll 4
    for (int l = l0; l < l0 + 128; ++l)
        acc += expf(sc[l] - m) * enc[(size_t)l * H + h];
    atomicAdd(&ws[OFF_X + h], acc * inv);
}

__global__ __launch_bounds__(256) void k_gates(const float* __restrict__ Wih,
                                               const float* __restrict__ Whh,
                                               const float* __restrict__ bih,
                                               const float* __restrict__ bhh,
                                               const float* __restrict__ x, int Cx,
                                               const float* __restrict__ h,
                                               float* __restrict__ gi,
                                               float* __restrict__ gh) {
    int b = blockIdx.x;
    bool isH = (b >= 768);
    int row  = (isH ? b - 768 : b) * 4 + (threadIdx.x >> 6);
    int lane = threadIdx.x & 63;
    const float* W    = isH ? Whh : Wih;
    const float* v    = isH ? h : x;
    const float* bias = isH ? bhh : bih;
    int C       = isH ? H : Cx;
    float* out  = isH ? gh : gi;
    const float4* Wr = (const float4*)(W + (size_t)row * C);
    const float4* v4 = (const float4*)v;
    float acc = 0.f;
    int n4 = C >> 2;
    for (int c = lane; c < n4; c += 64) {
        float4 wv4 = Wr[c], xx = v4[c];
        acc += wv4.x * xx.x + wv4.y * xx.y + wv4.z * xx.z + wv4.w * xx.w;
    }
#pragma unroll
    for (int off = 32; off; off >>= 1) acc += __shfl_down(acc, off);
    if (lane == 0) out[row] = acc + bias[row];
}

__global__ __launch_bounds__(256) void k_gates1(const float* __restrict__ Wih,
                                                const float* __restrict__ Whh,
                                                const float* __restrict__ bih,
                                                const float* __restrict__ bhh,
                                                const float* __restrict__ gi0,
                                                const float* __restrict__ gh0,
                                                const float* __restrict__ hid,
                                                float* __restrict__ h0n_out,
                                                float* __restrict__ gi,
                                                float* __restrict__ gh) {
    const int b = blockIdx.x, t = threadIdx.x;
    const int lane = t & 63;
    if (b < 768) {
        __shared__ float xs[H];
#pragma unroll
        for (int jj = 0; jj < 4; ++jj) {
            int j = t + jj * 256;
            float r = 1.f / (1.f + expf(-(gi0[j] + gh0[j])));
            float z = 1.f / (1.f + expf(-(gi0[H + j] + gh0[H + j])));
            float n = tanhf(gi0[2 * H + j] + r * gh0[2 * H + j]);
            float h0 = (1.f - z) * n + z * hid[j];
            xs[j] = h0;
            if (b == 0) h0n_out[j] = h0;
        }
        __syncthreads();
        int row = b * 4 + (t >> 6);
        const float4* Wr = (const float4*)(Wih + (size_t)row * H);
        float acc = 0.f;
        for (int c = lane; c < H / 4; c += 64) {
            float4 wv4 = Wr[c];
            float4 xx = *(const float4*)&xs[c * 4];
            acc += wv4.x * xx.x + wv4.y * xx.y + wv4.z * xx.z + wv4.w * xx.w;
        }
#pragma unroll
        for (int off = 32; off; off >>= 1) acc += __shfl_down(acc, off);
        if (lane == 0) gi[row] = acc + bih[row];
    } else {
        int row = (b - 768) * 4 + (t >> 6);
        const float4* Wr = (const float4*)(Whh + (size_t)row * H);
        const float4* h4 = (const float4*)(hid + H);
        float acc = 0.f;
        for (int c = lane; c < H / 4; c += 64) {
            float4 wv4 = Wr[c], xx = h4[c];
            acc += wv4.x * xx.x + wv4.y * xx.y + wv4.z * xx.z + wv4.w * xx.w;
        }
#pragma unroll
        for (int off = 32; off; off >>= 1) acc += __shfl_down(acc, off);
        if (lane == 0) gh[row] = acc + bhh[row];
    }
}

__global__ __launch_bounds__(256) void k_logits(const float* __restrict__ Wd,
                                                const float* __restrict__ bd,
                                                const float* __restrict__ gi1,
                                                const float* __restrict__ gh1,
                                                const float* __restrict__ hid,
                                                float* __restrict__ h1n_out,
                                                float* __restrict__ ws) {
    __shared__ float h1s[H];
    const int t = threadIdx.x;
#pragma unroll
    for (int jj = 0; jj < 4; ++jj) {
        int j = t + jj * 256;
        float r = 1.f / (1.f + expf(-(gi1[j] + gh1[j])));
        float z = 1.f / (1.f + expf(-(gi1[H + j] + gh1[H + j])));
        float n = tanhf(gi1[2 * H + j] + r * gh1[2 * H + j]);
        float h1 = (1.f - z) * n + z * hid[H + j];
        h1s[j] = h1;
        if (blockIdx.x == 0 && blockIdx.y == 0) h1n_out[j] = h1;
    }
    __syncthreads();
    int v = blockIdx.x * 256 + t;
    if (v >= V) return;
    int k0 = blockIdx.y * 128;
    float acc = (blockIdx.y == 0) ? bd[v] : 0.f;
    const float* Wp = Wd + (size_t)k0 * V + v;
#pragma unroll 8
    for (int k = 0; k < 128; ++k) acc += h1s[k0 + k] * Wp[(size_t)k * V];
    atomicAdd(&ws[OFF_LOGITS + v], acc);
}

__global__ __launch_bounds__(1024) void k_logsoftmax(const float* __restrict__ lg,
                                                     float* __restrict__ out) {
    __shared__ float red[16];
    const int tid = threadIdx.x;
    float m = -1e30f;
    for (int v = tid; v < V; v += 1024) m = fmaxf(m, lg[v]);
#pragma unroll
    for (int off = 32; off; off >>= 1) m = fmaxf(m, __shfl_down(m, off));
    if ((tid & 63) == 0) red[tid >> 6] = m;
    __syncthreads();
    if (tid == 0) {
        float mm = red[0];
        for (int w = 1; w < 16; ++w) mm = fmaxf(mm, red[w]);
        red[0] = mm;
    }
    __syncthreads();
    m = red[0];
    __syncthreads();
    float s = 0.f;
    for (int v = tid; v < V; v += 1024) s += expf(lg[v] - m);
#pragma unroll
    for (int off = 32; off; off >>= 1) s += __shfl_down(s, off);
    if ((tid & 63) == 0) red[tid >> 6] = s;
    __syncthreads();
    if (tid == 0) {
        float tt = 0.f;
        for (int w = 0; w < 16; ++w) tt += red[w];
        red[0] = tt;
    }
    __syncthreads();
    float lse = m + logf(red[0]);
    for (int v = tid; v < V; v += 1024) out[v] = lg[v] - lse;
}

extern "C" void kernel_launch(void* const* d_in, const int* in_sizes, int n_in,
                              void* d_out, int out_size, void* d_ws, size_t ws_size,
                              hipStream_t stream) {
    const int*   tok  = (const int*)d_in[0];
    const float* hid  = (const float*)d_in[1];
    const float* enc  = (const float*)d_in[2];
    const float* emb  = (const float*)d_in[3];
    const float* Wq   = (const float*)d_in[4];
    const float* Wk   = (const float*)d_in[5];
    const float* wv   = (const float*)d_in[6];
    const float* Wih0 = (const float*)d_in[7];
    const float* Whh0 = (const float*)d_in[8];
    const float* bih0 = (const float*)d_in[9];
    const float* bhh0 = (const float*)d_in[10];
    const float* Wih1 = (const float*)d_in[11];
    const float* Whh1 = (const float*)d_in[12];
    const float* bih1 = (const float*)d_in[13];
    const float* bhh1 = (const float*)d_in[14];
    const float* Wd   = (const float*)d_in[15];
    const float* bd   = (const float*)d_in[16];
    float* out = (float*)d_out;
    float* ws  = (float*)d_ws;
    unsigned short* wkT = (unsigned short*)((char*)d_ws + OFF_WKT_BYTES);

    Prm prm{tok, hid, enc, emb, Wq, Wk, wv,
            Wih0, Whh0, bih0, bhh0, Wih1, Whh1, bih1, bhh1,
            Wd, bd, out, ws, wkT};
    void* args[] = {(void*)&prm};
    hipError_t e = hipLaunchCooperativeKernel((const void*)k_all,
                                              dim3(NB), dim3(NT), args, 0, stream);
    if (e != hipSuccess) {
        // fallback: original 8-dispatch chain
        (void)hipGetLastError();
        hipMemsetAsync(ws, 0, ZERO_FLOATS * sizeof(float), stream);
        k_prep<<<1092, 256, 0, stream>>>(tok, emb, hid, Wq, Wk, ws, wkT);
        k_gemm_scores<<<dim3(L / 64, H / 128), 256, 0, stream>>>(enc, wkT, wv, ws);
        k_context<<<dim3(4, 32), 256, 0, stream>>>(enc, ws);
        k_gates<<<1536, 256, 0, stream>>>(Wih0, Whh0, bih0, bhh0,
                                          ws + OFF_X, 2 * H, hid,
                                          ws + OFF_GI0, ws + OFF_GH0);
        k_gates1<<<1536, 256, 0, stream>>>(Wih1, Whh1, bih1, bhh1,
                                           ws + OFF_GI0, ws + OFF_GH0, hid,
                                           out + V, ws + OFF_GI1, ws + OFF_GH1);
        k_logits<<<dim3((V + 255) / 256, 8), 256, 0, stream>>>(Wd, bd,
                                           ws + OFF_GI1, ws + OFF_GH1, hid,
                                           out + V + H, ws);
        k_logsoftmax<<<1, 1024, 0, stream>>>(ws + OFF_LOGITS, out);
    }
}

// Round 2
// 518.197 us; speedup vs baseline: 1.9723x; 1.9723x over previous
//
#include <hip/hip_runtime.h>
#include <hip/hip_bf16.h>

#define H  1024
#define L  4096
#define V  50257

// workspace layout (floats)
#define OFF_QW     0                    // 1024   query @ Wq
#define OFF_SCORES 1024                 // 4096   raw scores (pre-softmax)
#define OFF_X      5120                 // 2048   x = concat(context, emb_relu)
#define OFF_GI0    7168                 // 3072
#define OFF_GH0    10240                // 3072
#define OFF_GI1    13312                // 3072
#define OFF_GH1    16384                // 3072
#define OFF_LOGITS 19456                // V
#define OFF_PMAX   (OFF_LOGITS + V)     // 69713  per-block lsm max partials (197)
#define OFF_PSUM   (OFF_PMAX + 256)     // 69969  per-block lsm sum partials (197)
#define ZERO_FLOATS (OFF_LOGITS + V)    // 69713 floats zeroed per call (QW..LOGITS)
#define OFF_WKT_BYTES 283008            // 16B-aligned; bf16 WkT[1024][1024] = 2 MB

typedef __bf16 bf8   __attribute__((ext_vector_type(8)));
typedef float  f32x16 __attribute__((ext_vector_type(16)));

__device__ inline unsigned int pack_bf16x2(float lo, float hi) {
    unsigned int ulo = __builtin_bit_cast(unsigned int, lo);
    unsigned int uhi = __builtin_bit_cast(unsigned int, hi);
    return ((uhi + 0x8000u) & 0xFFFF0000u) | ((ulo + 0x8000u) >> 16);
}
__device__ inline unsigned short cvt_bf16(float f) {
    unsigned int u = __builtin_bit_cast(unsigned int, f);
    return (unsigned short)((u + 0x8000u) >> 16);
}

// ============ prep: embed+relu | qW | WkT transpose | gh0 | gh1 ============
// gh0/gh1 depend only on inputs -> hoisted here to overlap with transpose.
// blocks [0,4): embed; [4,68): qW (4 j-blocks x 16 k-splits, atomic);
// [68,1092): WkT tiles; [1092,1860): gh0; [1860,2628): gh1
__global__ __launch_bounds__(256) void k_prep(const int* __restrict__ tok,
                                              const float* __restrict__ emb,
                                              const float* __restrict__ hid,
                                              const float* __restrict__ Wq,
                                              const float* __restrict__ Wk,
                                              const float* __restrict__ Whh0,
                                              const float* __restrict__ bhh0,
                                              const float* __restrict__ Whh1,
                                              const float* __restrict__ bhh1,
                                              float* __restrict__ ws,
                                              unsigned short* __restrict__ wkT) {
    __shared__ float tile[32][33];
    const int b = blockIdx.x, t = threadIdx.x;
    if (b < 4) {
        int j = b * 256 + t;
        float v = emb[(size_t)tok[0] * H + j];
        ws[OFF_X + H + j] = fmaxf(v, 0.f);
    } else if (b < 68) {
        int bb = b - 4;
        int j = (bb & 3) * 256 + t;
        int i0 = (bb >> 2) * 64;
        const float* q = hid + H;
        float acc = 0.f;
#pragma unroll 8
        for (int i = i0; i < i0 + 64; ++i) acc += q[i] * Wq[i * H + j];
        atomicAdd(&ws[OFF_QW + j], acc);
    } else if (b < 1092) {
        int tt = b - 68;              // 32x32 grid of 32x32 tiles
        int tk = tt & 31, tn = tt >> 5;
        int c = t & 31, r0 = t >> 5;
#pragma unroll
        for (int rr = 0; rr < 4; ++rr) {
            int r = r0 + rr * 8;
            tile[r][c] = Wk[(size_t)(tk * 32 + r) * H + tn * 32 + c];
        }
        __syncthreads();
#pragma unroll
        for (int rr = 0; rr < 4; ++rr) {
            int rn = r0 + rr * 8;     // output row n, col k; read tile[ck][rn]
            wkT[(size_t)(tn * 32 + rn) * H + tk * 32 + c] = cvt_bf16(tile[c][rn]);
        }
    } else {
        // gh = Whh @ h + bhh   (one 64-lane wave per output row)
        bool l1 = (b >= 1860);
        int row  = (b - (l1 ? 1860 : 1092)) * 4 + (t >> 6);
        int lane = t & 63;
        const float*  W  = l1 ? Whh1 : Whh0;
        const float*  bi = l1 ? bhh1 : bhh0;
        const float4* hv = (const float4*)(l1 ? hid + H : hid);
        const float4* Wr = (const float4*)(W + (size_t)row * H);
        float acc = 0.f;
#pragma unroll
        for (int c = lane; c < H / 4; c += 64) {
            float4 w = Wr[c], x = hv[c];
            acc += w.x * x.x + w.y * x.y + w.z * x.z + w.w * x.w;
        }
#pragma unroll
        for (int off = 32; off; off >>= 1) acc += __shfl_down(acc, off);
        if (lane == 0) ws[(l1 ? OFF_GH1 : OFF_GH0) + row] = acc + bi[row];
    }
}

// ============ scores GEMM: bf16 MFMA, tile 64x128, K-step 32 ============
// grid (L/64=64, H/128=8), 256 threads (4 waves). Epilogue: tanh(+qW)*wv
// reduced over n, atomicAdd into raw scores.
__global__ __launch_bounds__(256) void k_gemm_scores(const float* __restrict__ enc,
                                                     const unsigned short* __restrict__ wkT,
                                                     const float* __restrict__ wv,
                                                     float* __restrict__ ws) {
    __shared__ unsigned short As[64][40];   // [m][k] bf16, +8 pad (4-way conflict)
    __shared__ unsigned short Bs[128][40];  // [n][k] bf16
    const int t = threadIdx.x, lane = t & 63, w = t >> 6;
    const int m0 = blockIdx.x * 64, n0 = blockIdx.y * 128;

    f32x16 acc0 = {}, acc1 = {};

    const int ar = t >> 2, akq = (t & 3) * 8;     // A: 64x32 fp32 -> bf16
    const int bn = t >> 1, bkh = (t & 1) * 16;    // B: 128x32 bf16 copy

    const int r0 = (w & 1) * 32, c0 = (w >> 1) * 64;
    const int mrow = r0 + (lane & 31);
    const int nrow0 = c0 + (lane & 31), nrow1 = nrow0 + 32;

    for (int k0 = 0; k0 < H; k0 += 32) {
        float4 fa = *(const float4*)(enc + (size_t)(m0 + ar) * H + k0 + akq);
        float4 fb = *(const float4*)(enc + (size_t)(m0 + ar) * H + k0 + akq + 4);
        uint4 wb0 = *(const uint4*)(wkT + (size_t)(n0 + bn) * H + k0 + bkh);
        uint4 wb1 = *(const uint4*)(wkT + (size_t)(n0 + bn) * H + k0 + bkh + 8);
        __syncthreads();   // previous-iter LDS reads done before overwrite
        uint4 pa;
        pa.x = pack_bf16x2(fa.x, fa.y); pa.y = pack_bf16x2(fa.z, fa.w);
        pa.z = pack_bf16x2(fb.x, fb.y); pa.w = pack_bf16x2(fb.z, fb.w);
        *(uint4*)&As[ar][akq] = pa;
        *(uint4*)&Bs[bn][bkh] = wb0;
        *(uint4*)&Bs[bn][bkh + 8] = wb1;
        __syncthreads();
#pragma unroll
        for (int kk = 0; kk < 2; ++kk) {
            int kb = kk * 16 + (lane >> 5) * 8;
            bf8 a  = *(const bf8*)&As[mrow][kb];
            bf8 b0 = *(const bf8*)&Bs[nrow0][kb];
            bf8 b1 = *(const bf8*)&Bs[nrow1][kb];
            acc0 = __builtin_amdgcn_mfma_f32_32x32x16_bf16(a, b0, acc0, 0, 0, 0);
            acc1 = __builtin_amdgcn_mfma_f32_32x32x16_bf16(a, b1, acc1, 0, 0, 0);
        }
    }

    // epilogue: s[l] += sum_n tanh(acc+qW[n])*wv[n]
    const int n_a = n0 + nrow0, n_b = n0 + nrow1;
    float qwa = ws[OFF_QW + n_a], qwb = ws[OFF_QW + n_b];
    float wva = wv[n_a], wvb = wv[n_b];
    const int rbase = m0 + r0 + 4 * (lane >> 5);
#pragma unroll
    for (int reg = 0; reg < 16; ++reg) {
        float s = tanhf(acc0[reg] + qwa) * wva + tanhf(acc1[reg] + qwb) * wvb;
#pragma unroll
        for (int msk = 1; msk < 32; msk <<= 1) s += __shfl_xor(s, msk);
        if ((lane & 31) == 0) {
            int l = rbase + (reg & 3) + 8 * (reg >> 2);
            atomicAdd(&ws[OFF_SCORES + l], s);
        }
    }
}

// ============ context with inline softmax (probs staged in LDS) ====
// grid (4 h-blocks, 32 l-splits of 128)
__global__ __launch_bounds__(256) void k_context(const float* __restrict__ enc,
                                                 float* __restrict__ ws) {
    __shared__ float red[4];
    __shared__ float ps[128];
    const int t = threadIdx.x;
    const float* sc = ws + OFF_SCORES;

    float m = -1e30f;
#pragma unroll
    for (int i = 0; i < 16; ++i) m = fmaxf(m, sc[t + i * 256]);
#pragma unroll
    for (int msk = 1; msk < 64; msk <<= 1) m = fmaxf(m, __shfl_xor(m, msk));
    if ((t & 63) == 0) red[t >> 6] = m;
    __syncthreads();
    m = fmaxf(fmaxf(red[0], red[1]), fmaxf(red[2], red[3]));
    __syncthreads();

    float s = 0.f;
#pragma unroll
    for (int i = 0; i < 16; ++i) s += expf(sc[t + i * 256] - m);
#pragma unroll
    for (int msk = 1; msk < 64; msk <<= 1) s += __shfl_xor(s, msk);
    if ((t & 63) == 0) red[t >> 6] = s;
    __syncthreads();
    float inv = 1.f / (red[0] + red[1] + red[2] + red[3]);

    const int l0 = blockIdx.y * 128;
    if (t < 128) ps[t] = expf(sc[l0 + t] - m) * inv;   // probs once per block
    __syncthreads();

    const int h = blockIdx.x * 256 + t;
    float acc = 0.f;
#pragma unroll 4
    for (int l = 0; l < 128; ++l)
        acc += ps[l] * enc[(size_t)(l0 + l) * H + h];
    atomicAdd(&ws[OFF_X + h], acc);
}

// ============ gi0 = Wih0 @ x + bih0 (768 blocks, 4 rows each) ============
__global__ __launch_bounds__(256) void k_gi0(const float* __restrict__ Wih,
                                             const float* __restrict__ bih,
                                             const float* __restrict__ ws_x,
                                             float* __restrict__ gi) {
    int row = blockIdx.x * 4 + (threadIdx.x >> 6);
    int lane = threadIdx.x & 63;
    const float4* Wr = (const float4*)(Wih + (size_t)row * (2 * H));
    const float4* v4 = (const float4*)ws_x;
    float acc = 0.f;
#pragma unroll
    for (int c = lane; c < 2 * H / 4; c += 64) {
        float4 w = Wr[c], xx = v4[c];
        acc += w.x * xx.x + w.y * xx.y + w.z * xx.z + w.w * xx.w;
    }
#pragma unroll
    for (int off = 32; off; off >>= 1) acc += __shfl_down(acc, off);
    if (lane == 0) gi[row] = acc + bih[row];
}

// ============ combine0 -> h0n ; gi1 = Wih1 @ h0n (768 blocks) ============
__global__ __launch_bounds__(256) void k_gi1(const float* __restrict__ Wih,
                                             const float* __restrict__ bih,
                                             const float* __restrict__ gi0,
                                             const float* __restrict__ gh0,
                                             const float* __restrict__ hid,
                                             float* __restrict__ h0n_out,
                                             float* __restrict__ gi) {
    __shared__ float xs[H];
    const int b = blockIdx.x, t = threadIdx.x, lane = t & 63;
#pragma unroll
    for (int jj = 0; jj < 4; ++jj) {
        int j = t + jj * 256;
        float r = 1.f / (1.f + expf(-(gi0[j] + gh0[j])));
        float z = 1.f / (1.f + expf(-(gi0[H + j] + gh0[H + j])));
        float n = tanhf(gi0[2 * H + j] + r * gh0[2 * H + j]);
        float h0 = (1.f - z) * n + z * hid[j];
        xs[j] = h0;
        if (b == 0) h0n_out[j] = h0;
    }
    __syncthreads();
    int row = b * 4 + (t >> 6);
    const float4* Wr = (const float4*)(Wih + (size_t)row * H);
    float acc = 0.f;
#pragma unroll
    for (int c = lane; c < H / 4; c += 64) {
        float4 w = Wr[c];
        float4 xx = *(const float4*)&xs[c * 4];
        acc += w.x * xx.x + w.y * xx.y + w.z * xx.z + w.w * xx.w;
    }
#pragma unroll
    for (int off = 32; off; off >>= 1) acc += __shfl_down(acc, off);
    if (lane == 0) gi[row] = acc + bih[row];
}

// ============ combine1 -> h1n ; logits (2 ILP streams) ============
// grid (99 v-blocks of 512, 8 k-splits of 128)
__global__ __launch_bounds__(256) void k_logits(const float* __restrict__ Wd,
                                                const float* __restrict__ bd,
                                                const float* __restrict__ gi1,
                                                const float* __restrict__ gh1,
                                                const float* __restrict__ hid,
                                                float* __restrict__ h1n_out,
                                                float* __restrict__ ws) {
    __shared__ float h1s[H];
    const int t = threadIdx.x;
#pragma unroll
    for (int jj = 0; jj < 4; ++jj) {
        int j = t + jj * 256;
        float r = 1.f / (1.f + expf(-(gi1[j] + gh1[j])));
        float z = 1.f / (1.f + expf(-(gi1[H + j] + gh1[H + j])));
        float n = tanhf(gi1[2 * H + j] + r * gh1[2 * H + j]);
        float h1 = (1.f - z) * n + z * hid[H + j];
        h1s[j] = h1;
        if (blockIdx.x == 0 && blockIdx.y == 0) h1n_out[j] = h1;
    }
    __syncthreads();
    const int v0 = blockIdx.x * 512, k0 = blockIdx.y * 128;
    const int va = v0 + t, vb = v0 + 256 + t;
    const int vac = va < V ? va : V - 1;     // clamp: harmless dup loads in tail
    const int vbc = vb < V ? vb : V - 1;
    float acca = 0.f, accb = 0.f;
    const float* Wp = Wd + (size_t)k0 * V;
#pragma unroll 8
    for (int k = 0; k < 128; ++k) {          // 2 streams -> 16 loads in flight
        float xk = h1s[k0 + k];
        const float* row = Wp + (size_t)k * V;
        acca += xk * row[vac];
        accb += xk * row[vbc];
    }
    if (va < V) atomicAdd(&ws[OFF_LOGITS + va], acca + (k0 == 0 ? bd[va] : 0.f));
    if (vb < V) atomicAdd(&ws[OFF_LOGITS + vb], accb + (k0 == 0 ? bd[vb] : 0.f));
}

// ============ log_softmax stage 1: per-block (max, expsum) partials ======
// grid 197, one element per thread
__global__ __launch_bounds__(256) void k_lsm1(const float* __restrict__ lg,
                                              float* __restrict__ ws) {
    __shared__ float red[4];
    const int b = blockIdx.x, t = threadIdx.x;
    const int g = b * 256 + t;
    float x = (g < V) ? lg[g] : -1e30f;

    float m = x;
#pragma unroll
    for (int msk = 1; msk < 64; msk <<= 1) m = fmaxf(m, __shfl_xor(m, msk));
    if ((t & 63) == 0) red[t >> 6] = m;
    __syncthreads();
    m = fmaxf(fmaxf(red[0], red[1]), fmaxf(red[2], red[3]));
    __syncthreads();

    float s = (g < V) ? expf(x - m) : 0.f;
#pragma unroll
    for (int msk = 1; msk < 64; msk <<= 1) s += __shfl_xor(s, msk);
    if ((t & 63) == 0) red[t >> 6] = s;
    __syncthreads();
    if (t == 0) {
        ws[OFF_PMAX + b] = m;
        ws[OFF_PSUM + b] = red[0] + red[1] + red[2] + red[3];
    }
}

// ============ log_softmax stage 2: reduce partials (redundant per block),
// write out[v] = lg[v] - lse.  grid 197 ============
__global__ __launch_bounds__(256) void k_lsm2(const float* __restrict__ lg,
                                              const float* __restrict__ ws,
                                              float* __restrict__ out) {
    __shared__ float red[4];
    const int b = blockIdx.x, t = threadIdx.x;

    float pm = (t < 197) ? ws[OFF_PMAX + t] : -1e30f;
    float m = pm;
#pragma unroll
    for (int msk = 1; msk < 64; msk <<= 1) m = fmaxf(m, __shfl_xor(m, msk));
    if ((t & 63) == 0) red[t >> 6] = m;
    __syncthreads();
    m = fmaxf(fmaxf(red[0], red[1]), fmaxf(red[2], red[3]));
    __syncthreads();

    float s = (t < 197) ? ws[OFF_PSUM + t] * expf(pm - m) : 0.f;
#pragma unroll
    for (int msk = 1; msk < 64; msk <<= 1) s += __shfl_xor(s, msk);
    if ((t & 63) == 0) red[t >> 6] = s;
    __syncthreads();
    float lse = m + logf(red[0] + red[1] + red[2] + red[3]);

    const int g = b * 256 + t;
    if (g < V) out[g] = lg[g] - lse;
}

extern "C" void kernel_launch(void* const* d_in, const int* in_sizes, int n_in,
                              void* d_out, int out_size, void* d_ws, size_t ws_size,
                              hipStream_t stream) {
    const int*   tok  = (const int*)d_in[0];
    const float* hid  = (const float*)d_in[1];   // [2,1,H]
    const float* enc  = (const float*)d_in[2];   // [L,H]
    const float* emb  = (const float*)d_in[3];   // [V,H]
    const float* Wq   = (const float*)d_in[4];
    const float* Wk   = (const float*)d_in[5];
    const float* wv   = (const float*)d_in[6];
    const float* Wih0 = (const float*)d_in[7];
    const float* Whh0 = (const float*)d_in[8];
    const float* bih0 = (const float*)d_in[9];
    const float* bhh0 = (const float*)d_in[10];
    const float* Wih1 = (const float*)d_in[11];
    const float* Whh1 = (const float*)d_in[12];
    const float* bih1 = (const float*)d_in[13];
    const float* bhh1 = (const float*)d_in[14];
    const float* Wd   = (const float*)d_in[15];  // [H,V]
    const float* bd   = (const float*)d_in[16];
    float* out = (float*)d_out;                  // [V logp][H h0n][H h1n]
    float* ws  = (float*)d_ws;
    unsigned short* wkT = (unsigned short*)((char*)d_ws + OFF_WKT_BYTES);

    hipMemsetAsync(ws, 0, ZERO_FLOATS * sizeof(float), stream);

    k_prep<<<2628, 256, 0, stream>>>(tok, emb, hid, Wq, Wk,
                                     Whh0, bhh0, Whh1, bhh1, ws, wkT);
    k_gemm_scores<<<dim3(L / 64, H / 128), 256, 0, stream>>>(enc, wkT, wv, ws);
    k_context<<<dim3(4, 32), 256, 0, stream>>>(enc, ws);
    k_gi0<<<768, 256, 0, stream>>>(Wih0, bih0, ws + OFF_X, ws + OFF_GI0);
    k_gi1<<<768, 256, 0, stream>>>(Wih1, bih1, ws + OFF_GI0, ws + OFF_GH0,
                                   hid, out + V, ws + OFF_GI1);
    k_logits<<<dim3(99, 8), 256, 0, stream>>>(Wd, bd, ws + OFF_GI1, ws + OFF_GH1,
                                              hid, out + V + H, ws);
    k_lsm1<<<197, 256, 0, stream>>>(ws + OFF_LOGITS, ws);
    k_lsm2<<<197, 256, 0, stream>>>(ws + OFF_LOGITS, ws, out);
}